// Round 3
// baseline (398.853 us; speedup 1.0000x reference)
//
#include <hip/hip_runtime.h>
#include <hip/hip_bf16.h>

// ===== Problem dims =====
// B=32, L=512 -> M = 16384 rows. Inputs fp32, OUTPUTS fp32.
// ho = [emb(500) | lang(100)] pad-> K=640 ; hidden K=800 ; aux_cat K=640
// GEMM1: N=500 pad 512 (arc 100 + lab 400) ; GEMM2: N=500 pad 512 ; GEMM3: N=820 pad 896
// MFMA operands fp16 (mfma_f32_16x16x32_f16), fp32 accumulate, fp32 out.
// Outputs (fp32, flat concat): arcs[32,512,513] | proj_label[16384,400] |
//   upos[16384,20] | xpos[16384,300] | attrs[16384,500]  => 28,393,472 elems

using f16   = _Float16;
using f16x8 = __attribute__((ext_vector_type(8))) _Float16;  // 8 f16 (4 VGPRs)
using f32x4 = __attribute__((ext_vector_type(4))) float;     // MFMA acc

#define M_ROWS 16384

__device__ __forceinline__ f16 f2h(float f) { return (f16)f; }  // RNE v_cvt_f16_f32

// ---------------------------------------------------------------------------
// Prep: pack padded fp16 weight matrices [Npad, Kpad] + fp32 biases into ws
// ---------------------------------------------------------------------------
__global__ __launch_bounds__(256) void prep_weights(
    const float* __restrict__ W_arc, const float* __restrict__ b_arc,
    const float* __restrict__ W_lab, const float* __restrict__ b_lab,
    const float* __restrict__ W_aux, const float* __restrict__ b_aux,
    const float* __restrict__ W_upos, const float* __restrict__ b_upos,
    const float* __restrict__ W_xpos, const float* __restrict__ b_xpos,
    const float* __restrict__ W_attrs, const float* __restrict__ b_attrs,
    f16* __restrict__ W_proj, f16* __restrict__ W_auxp, f16* __restrict__ W_heads,
    float* __restrict__ bias_proj, float* __restrict__ bias_aux, float* __restrict__ bias_heads)
{
  int idx = blockIdx.x * 256 + threadIdx.x;

  if (idx < 512 * 640) {                       // W_proj [512,640]
    int n = idx / 640, k = idx - n * 640;
    f16 v = (f16)0.f;
    if (k < 600) {
      if (n < 100)      v = f2h(W_arc[n * 600 + k]);
      else if (n < 500) v = f2h(W_lab[(n - 100) * 600 + k]);
    }
    W_proj[idx] = v;
    return;
  }
  idx -= 512 * 640;

  if (idx < 512 * 800) {                       // W_auxp [512,800]
    int n = idx / 800;
    W_auxp[idx] = (n < 500) ? f2h(W_aux[idx]) : (f16)0.f;
    return;
  }
  idx -= 512 * 800;

  if (idx < 896 * 640) {                       // W_heads [896,640]
    int n = idx / 640, k = idx - n * 640;
    f16 v = (f16)0.f;
    if (k < 600) {
      if (n < 20)       v = f2h(W_upos[n * 600 + k]);
      else if (n < 320) v = f2h(W_xpos[(n - 20) * 600 + k]);
      else if (n < 820) v = f2h(W_attrs[(n - 320) * 600 + k]);
    }
    W_heads[idx] = v;
    return;
  }
  idx -= 896 * 640;

  if (idx < 512) {                             // bias_proj (fp32)
    float v = 0.f;
    if (idx < 100)      v = b_arc[idx];
    else if (idx < 500) v = b_lab[idx - 100];
    bias_proj[idx] = v;
    return;
  }
  idx -= 512;
  if (idx < 512) {                             // bias_aux (fp32)
    bias_aux[idx] = (idx < 500) ? b_aux[idx] : 0.f;
    return;
  }
  idx -= 512;
  if (idx < 896) {                             // bias_heads (fp32)
    float v = 0.f;
    if (idx < 20)       v = b_upos[idx];
    else if (idx < 320) v = b_xpos[idx - 20];
    else if (idx < 820) v = b_attrs[idx - 320];
    bias_heads[idx] = v;
  }
}

// ---------------------------------------------------------------------------
// Build ho_pad [16384,640] f16 = [emb | lang | 0]; fill aux_cat cols [500,640)
// (aux_cat cols [0,500) are written later by GEMM2's epilogue)
// ---------------------------------------------------------------------------
__global__ __launch_bounds__(256) void build_concat(
    const float* __restrict__ emb,
    const float* __restrict__ lang_table,
    const int* __restrict__ lang_ids,
    f16* __restrict__ ho, f16* __restrict__ aux_cat)
{
  int idx = blockIdx.x * 256 + threadIdx.x;    // < 16384*640 exactly
  int row = idx / 640, k = idx - row * 640;
  int b = row >> 9;
  f16 v;
  if (k < 500)       v = f2h(emb[(size_t)row * 500 + k]);
  else if (k < 600)  v = f2h(lang_table[lang_ids[b] * 100 + (k - 500)]);
  else               v = (f16)0.f;
  ho[idx] = v;
  if (k >= 500) aux_cat[idx] = (k < 600) ? v : (f16)0.f;
}

// ---------------------------------------------------------------------------
// MFMA GEMM: C[M,Npad] = A[M,K] * B[Npad,K]^T  (+bias, optional tanh, scatter)
// 128x128 block tile, 4 waves of 64x64, BK=32, mfma_f32_16x16x32_f16.
// AF32: A is fp32 in global, converted to fp16 while staging into LDS.
// mode 0: tanh; col<100 -> proj_arc(f32 ws); 100<=col<500 -> out_label(f32)
// mode 1: tanh; col<500 -> aux_cat[row*640+col] (f16 ws)
// mode 2: col<20 upos | <320 xpos | <820 attrs (f32)
// ---------------------------------------------------------------------------
template <bool AF32>
__global__ __launch_bounds__(256) void gemm_mfma(
    const void* __restrict__ Av, const f16* __restrict__ B,
    const float* __restrict__ bias, int K, int mode,
    float* __restrict__ proj_arc, float* __restrict__ out_label,
    f16* __restrict__ aux_cat, float* __restrict__ out_upos,
    float* __restrict__ out_xpos, float* __restrict__ out_attrs)
{
  __shared__ __align__(16) f16 ldsA[128 * 32];
  __shared__ __align__(16) f16 ldsB[128 * 32];

  const int tid  = threadIdx.x;
  const int lane = tid & 63;
  const int wave = tid >> 6;          // 0..3
  const int wm = wave >> 1, wn = wave & 1;
  const int m16 = lane & 15, quad = lane >> 4;
  const int bm = blockIdx.x, bn = blockIdx.y;

  f32x4 acc[4][4] = {};

  // staging: chunk q in [0,512): row=q>>2, 8-elem col group q&3; thread does q=tid, tid+256
  const int q0 = tid, q1 = tid + 256;
  const size_t offA0 = (size_t)(bm * 128 + (q0 >> 2)) * K + (q0 & 3) * 8;
  const size_t offA1 = (size_t)(bm * 128 + (q1 >> 2)) * K + (q1 & 3) * 8;
  const f16* gB0 = B + (size_t)(bn * 128 + (q0 >> 2)) * K + (q0 & 3) * 8;
  const f16* gB1 = B + (size_t)(bn * 128 + (q1 >> 2)) * K + (q1 & 3) * 8;

  for (int k0 = 0; k0 < K; k0 += 32) {
    uint4 a0, a1;
    if (AF32) {
      const float* fA = (const float*)Av;
      float4 lo0 = *(const float4*)(fA + offA0 + k0);
      float4 hi0 = *(const float4*)(fA + offA0 + k0 + 4);
      float4 lo1 = *(const float4*)(fA + offA1 + k0);
      float4 hi1 = *(const float4*)(fA + offA1 + k0 + 4);
      union { f16 h[8]; uint4 v; } u0, u1;
      u0.h[0] = f2h(lo0.x); u0.h[1] = f2h(lo0.y); u0.h[2] = f2h(lo0.z); u0.h[3] = f2h(lo0.w);
      u0.h[4] = f2h(hi0.x); u0.h[5] = f2h(hi0.y); u0.h[6] = f2h(hi0.z); u0.h[7] = f2h(hi0.w);
      u1.h[0] = f2h(lo1.x); u1.h[1] = f2h(lo1.y); u1.h[2] = f2h(lo1.z); u1.h[3] = f2h(lo1.w);
      u1.h[4] = f2h(hi1.x); u1.h[5] = f2h(hi1.y); u1.h[6] = f2h(hi1.z); u1.h[7] = f2h(hi1.w);
      a0 = u0.v; a1 = u1.v;
    } else {
      const f16* sA = (const f16*)Av;
      a0 = *(const uint4*)(sA + offA0 + k0);
      a1 = *(const uint4*)(sA + offA1 + k0);
    }
    uint4 b0 = *(const uint4*)(gB0 + k0);
    uint4 b1 = *(const uint4*)(gB1 + k0);
    __syncthreads();                 // previous iteration's LDS reads done
    ((uint4*)ldsA)[q0] = a0;  ((uint4*)ldsA)[q1] = a1;
    ((uint4*)ldsB)[q0] = b0;  ((uint4*)ldsB)[q1] = b1;
    __syncthreads();

    f16x8 af[4], bfr[4];
#pragma unroll
    for (int i = 0; i < 4; ++i)
      af[i] = *(const f16x8*)&ldsA[(wm * 64 + i * 16 + m16) * 32 + quad * 8];
#pragma unroll
    for (int j = 0; j < 4; ++j)
      bfr[j] = *(const f16x8*)&ldsB[(wn * 64 + j * 16 + m16) * 32 + quad * 8];
#pragma unroll
    for (int i = 0; i < 4; ++i)
#pragma unroll
      for (int j = 0; j < 4; ++j)
        acc[i][j] = __builtin_amdgcn_mfma_f32_16x16x32_f16(af[i], bfr[j], acc[i][j], 0, 0, 0);
  }

  // epilogue: C row = bm*128 + wm*64 + i*16 + quad*4 + r ; col = bn*128 + wn*64 + j*16 + m16
  const int row0 = bm * 128 + wm * 64 + quad * 4;
  const int col0 = bn * 128 + wn * 64 + m16;
#pragma unroll
  for (int i = 0; i < 4; ++i) {
#pragma unroll
    for (int j = 0; j < 4; ++j) {
      const int col = col0 + j * 16;
      const float bcol = bias[col];
#pragma unroll
      for (int r = 0; r < 4; ++r) {
        const int row = row0 + i * 16 + r;
        float v = acc[i][j][r] + bcol;
        if (mode == 0) {
          v = tanhf(v);
          if (col < 100)       proj_arc[(size_t)row * 100 + col] = v;
          else if (col < 500)  out_label[(size_t)row * 400 + col - 100] = v;
        } else if (mode == 1) {
          v = tanhf(v);
          if (col < 500)       aux_cat[(size_t)row * 640 + col] = f2h(v);
        } else {
          if (col < 20)        out_upos[(size_t)row * 20 + col] = v;
          else if (col < 320)  out_xpos[(size_t)row * 300 + col - 20] = v;
          else if (col < 820)  out_attrs[(size_t)row * 500 + col - 320] = v;
        }
      }
    }
  }
}

// ---------------------------------------------------------------------------
// s1[row] = proj_arc[row,:] . w_head[0:100] ; s2[row] = . w_head[100:200]
// ---------------------------------------------------------------------------
__global__ __launch_bounds__(256) void s1s2_kernel(
    const float* __restrict__ proj_arc, const float* __restrict__ w_head,
    float* __restrict__ s1, float* __restrict__ s2)
{
  int row = blockIdx.x * 256 + threadIdx.x;
  if (row >= M_ROWS) return;
  const float* pa = proj_arc + (size_t)row * 100;
  float a1 = 0.f, a2 = 0.f;
#pragma unroll 4
  for (int p = 0; p < 100; ++p) {
    float x = pa[p];
    a1 += x * w_head[p];
    a2 += x * w_head[100 + p];
  }
  s1[row] = a1;
  s2[row] = a2;
}

// ---------------------------------------------------------------------------
// arcs[b,i,0]=0 ; arcs[b,i,1+j] = s1[b,i] + s2[b,j] + b_head   (fp32 out)
// ---------------------------------------------------------------------------
__global__ __launch_bounds__(256) void arcs_kernel(
    const float* __restrict__ s1, const float* __restrict__ s2,
    const float* __restrict__ b_head, float* __restrict__ out)
{
  size_t idx = (size_t)blockIdx.x * 256 + threadIdx.x;   // < 16384*513 exactly
  size_t row = idx / 513;                                // b*512 + i
  int j = (int)(idx - row * 513);
  int b = (int)(row >> 9);
  float v = 0.f;
  if (j != 0) v = s1[row] + s2[((size_t)b << 9) + (j - 1)] + b_head[0];
  out[idx] = v;
}

// ---------------------------------------------------------------------------
extern "C" void kernel_launch(void* const* d_in, const int* in_sizes, int n_in,
                              void* d_out, int out_size, void* d_ws, size_t ws_size,
                              hipStream_t stream)
{
  const float* emb      = (const float*)d_in[0];   // [32,512,500]
  const float* hidden   = (const float*)d_in[1];   // [32,512,800]
  const int*   lang_ids = (const int*)d_in[2];     // [32]
  const float* lang_tab = (const float*)d_in[3];   // [8,100]
  const float* W_arc  = (const float*)d_in[4];
  const float* b_arc  = (const float*)d_in[5];
  const float* W_lab  = (const float*)d_in[6];
  const float* b_lab  = (const float*)d_in[7];
  const float* w_head = (const float*)d_in[8];
  const float* b_head = (const float*)d_in[9];
  const float* W_aux  = (const float*)d_in[10];
  const float* b_aux  = (const float*)d_in[11];
  const float* W_upos = (const float*)d_in[12];
  const float* b_upos = (const float*)d_in[13];
  const float* W_xpos = (const float*)d_in[14];
  const float* b_xpos = (const float*)d_in[15];
  const float* W_attrs = (const float*)d_in[16];
  const float* b_attrs = (const float*)d_in[17];

  char* ws = (char*)d_ws;
  f16* ho      = (f16*)(ws + 0);                  // 16384*640*2
  f16* aux_cat = (f16*)(ws + 20971520);           // 16384*640*2
  f16* W_proj  = (f16*)(ws + 41943040);           // 512*640*2
  f16* W_auxp  = (f16*)(ws + 42598400);           // 512*800*2
  f16* W_heads = (f16*)(ws + 43417600);           // 896*640*2
  float* bias_proj  = (float*)(ws + 44564480);    // 512*4
  float* bias_aux   = (float*)(ws + 44566528);    // 512*4
  float* bias_heads = (float*)(ws + 44568576);    // 896*4
  float* proj_arc   = (float*)(ws + 44572160);    // 16384*100*4
  float* s1         = (float*)(ws + 51125760);    // 16384*4
  float* s2         = (float*)(ws + 51191296);    // 16384*4
  // total ws use: 51,256,832 bytes

  float* out       = (float*)d_out;
  float* out_arcs  = out;                 // 8,404,992
  float* out_label = out + 8404992;       // 6,553,600
  float* out_upos  = out + 14958592;      //   327,680
  float* out_xpos  = out + 15286272;      // 4,915,200
  float* out_attrs = out + 20201472;      // 8,192,000

  prep_weights<<<5128, 256, 0, stream>>>(W_arc, b_arc, W_lab, b_lab, W_aux, b_aux,
                                         W_upos, b_upos, W_xpos, b_xpos, W_attrs, b_attrs,
                                         W_proj, W_auxp, W_heads,
                                         bias_proj, bias_aux, bias_heads);
  build_concat<<<40960, 256, 0, stream>>>(emb, lang_tab, lang_ids, ho, aux_cat);

  dim3 g1(128, 4);
  gemm_mfma<false><<<g1, 256, 0, stream>>>(ho, W_proj, bias_proj, 640, 0,
                                    proj_arc, out_label, nullptr, nullptr, nullptr, nullptr);
  s1s2_kernel<<<64, 256, 0, stream>>>(proj_arc, w_head, s1, s2);
  arcs_kernel<<<32832, 256, 0, stream>>>(s1, s2, b_head, out_arcs);

  dim3 g2(128, 4);
  gemm_mfma<true><<<g2, 256, 0, stream>>>(hidden, W_auxp, bias_aux, 800, 1,
                                    nullptr, nullptr, aux_cat, nullptr, nullptr, nullptr);
  dim3 g3(128, 7);
  gemm_mfma<false><<<g3, 256, 0, stream>>>(aux_cat, W_heads, bias_heads, 640, 2,
                                    nullptr, nullptr, nullptr, out_upos, out_xpos, out_attrs);
}

// Round 4
// 358.785 us; speedup vs baseline: 1.1117x; 1.1117x over previous
//
#include <hip/hip_runtime.h>
#include <hip/hip_bf16.h>

// ===== Problem dims =====
// B=32, L=512 -> M = 16384 rows. Inputs fp32, OUTPUTS fp32.
// ho = [emb(500) | lang(100)] pad-> K=640 ; hidden K=800 ; aux_cat K=640
// GEMM1: N=500 pad 512 (arc 100 + lab 400) ; GEMM2: N=500 pad 512 ; GEMM3: N=820 pad 896
// MFMA operands fp16 (mfma_f32_16x16x32_f16), fp32 accumulate, fp32 out.
// Outputs (fp32, flat concat): arcs[32,512,513] | proj_label[16384,400] |
//   upos[16384,20] | xpos[16384,300] | attrs[16384,500]  => 28,393,472 elems

using f16   = _Float16;
using f16x4 = __attribute__((ext_vector_type(4))) _Float16;
using f16x8 = __attribute__((ext_vector_type(8))) _Float16;  // 8 f16 (4 VGPRs)
using f32x4 = __attribute__((ext_vector_type(4))) float;     // MFMA acc

#define M_ROWS 16384

__device__ __forceinline__ f16 f2h(float f) { return (f16)f; }  // RNE v_cvt_f16_f32

// async global->LDS, 16B per lane; LDS dest = wave-uniform base + lane*16
__device__ __forceinline__ void async16(void* lds, const void* gp) {
  __builtin_amdgcn_global_load_lds(
      (const __attribute__((address_space(1))) unsigned int*)gp,
      (__attribute__((address_space(3))) unsigned int*)lds, 16, 0, 0);
}

// ---------------------------------------------------------------------------
// Prep: pack padded fp16 weight matrices [Npad, Kpad] + fp32 biases into ws
// ---------------------------------------------------------------------------
__global__ __launch_bounds__(256) void prep_weights(
    const float* __restrict__ W_arc, const float* __restrict__ b_arc,
    const float* __restrict__ W_lab, const float* __restrict__ b_lab,
    const float* __restrict__ W_aux, const float* __restrict__ b_aux,
    const float* __restrict__ W_upos, const float* __restrict__ b_upos,
    const float* __restrict__ W_xpos, const float* __restrict__ b_xpos,
    const float* __restrict__ W_attrs, const float* __restrict__ b_attrs,
    f16* __restrict__ W_proj, f16* __restrict__ W_auxp, f16* __restrict__ W_heads,
    float* __restrict__ bias_proj, float* __restrict__ bias_aux, float* __restrict__ bias_heads)
{
  int idx = blockIdx.x * 256 + threadIdx.x;

  if (idx < 512 * 640) {                       // W_proj [512,640]
    int n = idx / 640, k = idx - n * 640;
    f16 v = (f16)0.f;
    if (k < 600) {
      if (n < 100)      v = f2h(W_arc[n * 600 + k]);
      else if (n < 500) v = f2h(W_lab[(n - 100) * 600 + k]);
    }
    W_proj[idx] = v;
    return;
  }
  idx -= 512 * 640;

  if (idx < 512 * 800) {                       // W_auxp [512,800]
    int n = idx / 800;
    W_auxp[idx] = (n < 500) ? f2h(W_aux[idx]) : (f16)0.f;
    return;
  }
  idx -= 512 * 800;

  if (idx < 896 * 640) {                       // W_heads [896,640]
    int n = idx / 640, k = idx - n * 640;
    f16 v = (f16)0.f;
    if (k < 600) {
      if (n < 20)       v = f2h(W_upos[n * 600 + k]);
      else if (n < 320) v = f2h(W_xpos[(n - 20) * 600 + k]);
      else if (n < 820) v = f2h(W_attrs[(n - 320) * 600 + k]);
    }
    W_heads[idx] = v;
    return;
  }
  idx -= 896 * 640;

  if (idx < 512) {                             // bias_proj (fp32)
    float v = 0.f;
    if (idx < 100)      v = b_arc[idx];
    else if (idx < 500) v = b_lab[idx - 100];
    bias_proj[idx] = v;
    return;
  }
  idx -= 512;
  if (idx < 512) {                             // bias_aux (fp32)
    bias_aux[idx] = (idx < 500) ? b_aux[idx] : 0.f;
    return;
  }
  idx -= 512;
  if (idx < 896) {                             // bias_heads (fp32)
    float v = 0.f;
    if (idx < 20)       v = b_upos[idx];
    else if (idx < 320) v = b_xpos[idx - 20];
    else if (idx < 820) v = b_attrs[idx - 320];
    bias_heads[idx] = v;
  }
}

// ---------------------------------------------------------------------------
// Per-row input build (one block per row, vectorized):
//   ho[row,0:500)=f16(emb), [500:600)=f16(lang), [600:640)=0
//   aux_cat[row,500:600)=lang, [600:640)=0   (cols [0,500) from GEMM2 epilogue)
//   hid16[row,0:800) = f16(hidden)
// ---------------------------------------------------------------------------
__global__ __launch_bounds__(256) void build_inputs(
    const float* __restrict__ emb, const float* __restrict__ hidden,
    const float* __restrict__ lang_table, const int* __restrict__ lang_ids,
    f16* __restrict__ ho, f16* __restrict__ aux_cat, f16* __restrict__ hid16)
{
  const int row = blockIdx.x;                 // 16384
  const int t = threadIdx.x;                  // 256
  const int b = row >> 9;
  const float* erow = emb + (size_t)row * 500;
  const float* hrow = hidden + (size_t)row * 800;
  f16* horow  = ho + (size_t)row * 640;
  f16* acrow  = aux_cat + (size_t)row * 640;
  f16* h16row = hid16 + (size_t)row * 800;

  if (t < 125) {                              // emb cols [0,500)
    float4 v = *(const float4*)(erow + 4 * t);
    f16x4 h = { f2h(v.x), f2h(v.y), f2h(v.z), f2h(v.w) };
    *(f16x4*)(horow + 4 * t) = h;
  } else if (t < 150) {                       // lang cols [500,600)
    int j = (t - 125) * 4;
    const float* lrow = lang_table + lang_ids[b] * 100;
    float4 v = *(const float4*)(lrow + j);
    f16x4 h = { f2h(v.x), f2h(v.y), f2h(v.z), f2h(v.w) };
    *(f16x4*)(horow + 500 + j) = h;
    *(f16x4*)(acrow + 500 + j) = h;
  } else if (t < 160) {                       // pad cols [600,640)
    int j = 600 + (t - 150) * 4;
    f16x4 z = { (f16)0.f, (f16)0.f, (f16)0.f, (f16)0.f };
    *(f16x4*)(horow + j) = z;
    *(f16x4*)(acrow + j) = z;
  }
  if (t < 200) {                              // hidden cols [0,800)
    float4 v = *(const float4*)(hrow + 4 * t);
    f16x4 h = { f2h(v.x), f2h(v.y), f2h(v.z), f2h(v.w) };
    *(f16x4*)(h16row + 4 * t) = h;
  }
}

// ---------------------------------------------------------------------------
// MFMA GEMM: C[M,Npad] = A[M,K] * B[Npad,K]^T  (+bias, optional tanh, scatter)
// 128x128 block tile, 4 waves of 64x64, BK=32, mfma_f32_16x16x32_f16.
// Staging via global_load_lds width=16 (async, no VGPR round-trip).
// mode 0: tanh; col<100 -> proj_arc(f32 ws); 100<=col<500 -> out_label(f32)
// mode 1: tanh; col<500 -> aux_cat[row*640+col] (f16 ws)
// mode 2: col<20 upos | <320 xpos | <820 attrs (f32)
// ---------------------------------------------------------------------------
__global__ __launch_bounds__(256) void gemm_mfma(
    const f16* __restrict__ A, const f16* __restrict__ B,
    const float* __restrict__ bias, int K, int mode,
    float* __restrict__ proj_arc, float* __restrict__ out_label,
    f16* __restrict__ aux_cat, float* __restrict__ out_upos,
    float* __restrict__ out_xpos, float* __restrict__ out_attrs)
{
  __shared__ __align__(16) f16 ldsA[128 * 32];
  __shared__ __align__(16) f16 ldsB[128 * 32];

  const int tid  = threadIdx.x;
  const int lane = tid & 63;
  const int wave = tid >> 6;          // 0..3
  const int wm = wave >> 1, wn = wave & 1;
  const int m16 = lane & 15, quad = lane >> 4;
  const int bm = blockIdx.x, bn = blockIdx.y;

  f32x4 acc[4][4] = {};

  // staging: chunk q in [0,512): row=q>>2, 8-elem col group q&3; this thread's
  // lanes supply chunks q0=tid (wave base wave*64) and q1=tid+256.
  const int q0 = tid, q1 = tid + 256;
  const f16* gA0 = A + (size_t)(bm * 128 + (q0 >> 2)) * K + (q0 & 3) * 8;
  const f16* gA1 = A + (size_t)(bm * 128 + (q1 >> 2)) * K + (q1 & 3) * 8;
  const f16* gB0 = B + (size_t)(bn * 128 + (q0 >> 2)) * K + (q0 & 3) * 8;
  const f16* gB1 = B + (size_t)(bn * 128 + (q1 >> 2)) * K + (q1 & 3) * 8;

  uint4* lA = (uint4*)ldsA;
  uint4* lB = (uint4*)ldsB;
  void* dA0 = (void*)&lA[wave * 64];
  void* dA1 = (void*)&lA[wave * 64 + 256];
  void* dB0 = (void*)&lB[wave * 64];
  void* dB1 = (void*)&lB[wave * 64 + 256];

  for (int k0 = 0; k0 < K; k0 += 32) {
    __syncthreads();                  // previous iteration's LDS reads done
    async16(dA0, gA0 + k0);
    async16(dA1, gA1 + k0);
    async16(dB0, gB0 + k0);
    async16(dB1, gB1 + k0);
    __syncthreads();                  // barrier drain waits vmcnt(0) -> LDS ready

    f16x8 af[4], bfr[4];
#pragma unroll
    for (int i = 0; i < 4; ++i)
      af[i] = *(const f16x8*)&ldsA[(wm * 64 + i * 16 + m16) * 32 + quad * 8];
#pragma unroll
    for (int j = 0; j < 4; ++j)
      bfr[j] = *(const f16x8*)&ldsB[(wn * 64 + j * 16 + m16) * 32 + quad * 8];
#pragma unroll
    for (int i = 0; i < 4; ++i)
#pragma unroll
      for (int j = 0; j < 4; ++j)
        acc[i][j] = __builtin_amdgcn_mfma_f32_16x16x32_f16(af[i], bfr[j], acc[i][j], 0, 0, 0);
  }

  // epilogue: C row = bm*128 + wm*64 + i*16 + quad*4 + r ; col = bn*128 + wn*64 + j*16 + m16
  const int row0 = bm * 128 + wm * 64 + quad * 4;
  const int col0 = bn * 128 + wn * 64 + m16;
#pragma unroll
  for (int i = 0; i < 4; ++i) {
#pragma unroll
    for (int j = 0; j < 4; ++j) {
      const int col = col0 + j * 16;
      const float bcol = bias[col];
#pragma unroll
      for (int r = 0; r < 4; ++r) {
        const int row = row0 + i * 16 + r;
        float v = acc[i][j][r] + bcol;
        if (mode == 0) {
          v = tanhf(v);
          if (col < 100)       proj_arc[(size_t)row * 100 + col] = v;
          else if (col < 500)  out_label[(size_t)row * 400 + col - 100] = v;
        } else if (mode == 1) {
          v = tanhf(v);
          if (col < 500)       aux_cat[(size_t)row * 640 + col] = f2h(v);
        } else {
          if (col < 20)        out_upos[(size_t)row * 20 + col] = v;
          else if (col < 320)  out_xpos[(size_t)row * 300 + col - 20] = v;
          else if (col < 820)  out_attrs[(size_t)row * 500 + col - 320] = v;
        }
      }
    }
  }
}

// ---------------------------------------------------------------------------
// s1[row] = proj_arc[row,:] . w_head[0:100] ; s2[row] = . w_head[100:200]
// ---------------------------------------------------------------------------
__global__ __launch_bounds__(256) void s1s2_kernel(
    const float* __restrict__ proj_arc, const float* __restrict__ w_head,
    float* __restrict__ s1, float* __restrict__ s2)
{
  int row = blockIdx.x * 256 + threadIdx.x;
  if (row >= M_ROWS) return;
  const float4* pa = (const float4*)(proj_arc + (size_t)row * 100);
  const float4* w1 = (const float4*)(w_head);
  const float4* w2 = (const float4*)(w_head + 100);
  float a1 = 0.f, a2 = 0.f;
#pragma unroll
  for (int p = 0; p < 25; ++p) {
    float4 x = pa[p], u = w1[p], v = w2[p];
    a1 += x.x * u.x + x.y * u.y + x.z * u.z + x.w * u.w;
    a2 += x.x * v.x + x.y * v.y + x.z * v.z + x.w * v.w;
  }
  s1[row] = a1;
  s2[row] = a2;
}

// ---------------------------------------------------------------------------
// arcs[b,i,0]=0 ; arcs[b,i,1+j] = s1[b,i] + s2[b,j] + b_head   (one block/row)
// ---------------------------------------------------------------------------
__global__ __launch_bounds__(256) void arcs_kernel(
    const float* __restrict__ s1, const float* __restrict__ s2,
    const float* __restrict__ b_head, float* __restrict__ out)
{
  const int row = blockIdx.x;                 // 16384 = b*512 + i
  const int b = row >> 9;
  const float s1v = s1[row] + b_head[0];
  const float* s2b = s2 + ((size_t)b << 9);
  float* orow = out + (size_t)row * 513;
  if (threadIdx.x == 0) orow[0] = 0.f;
#pragma unroll
  for (int j = threadIdx.x; j < 512; j += 256)
    orow[1 + j] = s1v + s2b[j];
}

// ---------------------------------------------------------------------------
extern "C" void kernel_launch(void* const* d_in, const int* in_sizes, int n_in,
                              void* d_out, int out_size, void* d_ws, size_t ws_size,
                              hipStream_t stream)
{
  const float* emb      = (const float*)d_in[0];   // [32,512,500]
  const float* hidden   = (const float*)d_in[1];   // [32,512,800]
  const int*   lang_ids = (const int*)d_in[2];     // [32]
  const float* lang_tab = (const float*)d_in[3];   // [8,100]
  const float* W_arc  = (const float*)d_in[4];
  const float* b_arc  = (const float*)d_in[5];
  const float* W_lab  = (const float*)d_in[6];
  const float* b_lab  = (const float*)d_in[7];
  const float* w_head = (const float*)d_in[8];
  const float* b_head = (const float*)d_in[9];
  const float* W_aux  = (const float*)d_in[10];
  const float* b_aux  = (const float*)d_in[11];
  const float* W_upos = (const float*)d_in[12];
  const float* b_upos = (const float*)d_in[13];
  const float* W_xpos = (const float*)d_in[14];
  const float* b_xpos = (const float*)d_in[15];
  const float* W_attrs = (const float*)d_in[16];
  const float* b_attrs = (const float*)d_in[17];

  char* ws = (char*)d_ws;
  f16* ho      = (f16*)(ws + 0);                  // 16384*640*2
  f16* aux_cat = (f16*)(ws + 20971520);           // 16384*640*2
  f16* W_proj  = (f16*)(ws + 41943040);           // 512*640*2
  f16* W_auxp  = (f16*)(ws + 42598400);           // 512*800*2
  f16* W_heads = (f16*)(ws + 43417600);           // 896*640*2
  float* bias_proj  = (float*)(ws + 44564480);    // 512*4
  float* bias_aux   = (float*)(ws + 44566528);    // 512*4
  float* bias_heads = (float*)(ws + 44568576);    // 896*4
  float* proj_arc   = (float*)(ws + 44572160);    // 16384*100*4
  float* s1         = (float*)(ws + 51125760);    // 16384*4
  float* s2         = (float*)(ws + 51191296);    // 16384*4
  // total ws use: 51,256,832 bytes (same as round 3, proven to fit)

  float* out       = (float*)d_out;
  float* out_arcs  = out;                 // 8,404,992
  float* out_label = out + 8404992;       // 6,553,600
  float* out_upos  = out + 14958592;      //   327,680
  float* out_xpos  = out + 15286272;      // 4,915,200
  float* out_attrs = out + 20201472;      // 8,192,000

  // hid16 (16384*800 f16 = 26.2 MB) stashed in the out_attrs region (32.8 MB):
  // written by build_inputs, read only by GEMM2, overwritten by GEMM3 epilogue.
  f16* hid16 = (f16*)(out + 20201472);

  prep_weights<<<5128, 256, 0, stream>>>(W_arc, b_arc, W_lab, b_lab, W_aux, b_aux,
                                         W_upos, b_upos, W_xpos, b_xpos, W_attrs, b_attrs,
                                         W_proj, W_auxp, W_heads,
                                         bias_proj, bias_aux, bias_heads);
  build_inputs<<<16384, 256, 0, stream>>>(emb, hidden, lang_tab, lang_ids,
                                          ho, aux_cat, hid16);

  dim3 g1(128, 4);
  gemm_mfma<<<g1, 256, 0, stream>>>(ho, W_proj, bias_proj, 640, 0,
                                    proj_arc, out_label, nullptr, nullptr, nullptr, nullptr);
  s1s2_kernel<<<64, 256, 0, stream>>>(proj_arc, w_head, s1, s2);
  arcs_kernel<<<16384, 256, 0, stream>>>(s1, s2, b_head, out_arcs);

  dim3 g2(128, 4);
  gemm_mfma<<<g2, 256, 0, stream>>>(hid16, W_auxp, bias_aux, 800, 1,
                                    nullptr, nullptr, aux_cat, nullptr, nullptr, nullptr);
  dim3 g3(128, 7);
  gemm_mfma<<<g3, 256, 0, stream>>>(aux_cat, W_heads, bias_heads, 640, 2,
                                    nullptr, nullptr, nullptr, out_upos, out_xpos, out_attrs);
}

// Round 5
// 337.062 us; speedup vs baseline: 1.1833x; 1.0644x over previous
//
#include <hip/hip_runtime.h>
#include <hip/hip_bf16.h>

// ===== Problem dims =====
// B=32, L=512 -> M = 16384 rows. Inputs fp32, OUTPUTS fp32.
// ho = [emb(500) | lang(100)] pad-> K=640 ; hidden K=800 ; aux_cat K=640
// GEMM1: N=500 pad 512 (arc 100 + lab 400), fused s1/s2 epilogue (proj_arc never materialized)
// GEMM2: N=500 pad 512 ; GEMM3: N=820 pad 896
// MFMA fp16 operands (mfma_f32_16x16x32_f16), fp32 accumulate, fp32 out.
// Double-buffered global_load_lds K-loop (1 barrier/iter, loads overlap MFMA).
// Outputs (fp32, flat concat): arcs[32,512,513] | proj_label[16384,400] |
//   upos[16384,20] | xpos[16384,300] | attrs[16384,500]  => 28,393,472 elems

using f16   = _Float16;
using f16x4 = __attribute__((ext_vector_type(4))) _Float16;
using f16x8 = __attribute__((ext_vector_type(8))) _Float16;  // 8 f16 (4 VGPRs)
using f32x4 = __attribute__((ext_vector_type(4))) float;     // MFMA acc

#define M_ROWS 16384

__device__ __forceinline__ f16 f2h(float f) { return (f16)f; }  // RNE v_cvt_f16_f32

// async global->LDS, 16B per lane; LDS dest = wave-uniform base + lane*16
__device__ __forceinline__ void async16(void* lds, const void* gp) {
  __builtin_amdgcn_global_load_lds(
      (const __attribute__((address_space(1))) unsigned int*)gp,
      (__attribute__((address_space(3))) unsigned int*)lds, 16, 0, 0);
}

// ---------------------------------------------------------------------------
// Fused setup: blocks [0,16384) build per-row activations (ho, aux_cat lang
// cols, hid16 = f16(hidden)); blocks [16384,17664) pack padded f16 weights
// (vectorized f16x4 quads); block 17664 packs fp32 biases.
// ---------------------------------------------------------------------------
__global__ __launch_bounds__(256) void setup_kernel(
    const float* __restrict__ emb, const float* __restrict__ hidden,
    const float* __restrict__ lang_table, const int* __restrict__ lang_ids,
    const float* __restrict__ W_arc, const float* __restrict__ b_arc,
    const float* __restrict__ W_lab, const float* __restrict__ b_lab,
    const float* __restrict__ W_aux, const float* __restrict__ b_aux,
    const float* __restrict__ W_upos, const float* __restrict__ b_upos,
    const float* __restrict__ W_xpos, const float* __restrict__ b_xpos,
    const float* __restrict__ W_attrs, const float* __restrict__ b_attrs,
    f16* __restrict__ ho, f16* __restrict__ aux_cat, f16* __restrict__ hid16,
    f16* __restrict__ W_proj, f16* __restrict__ W_auxp, f16* __restrict__ W_heads,
    float* __restrict__ bias_proj, float* __restrict__ bias_aux, float* __restrict__ bias_heads)
{
  const int blk = blockIdx.x, t = threadIdx.x;

  if (blk < 16384) {                           // ---- activation rows ----
    const int row = blk;
    const int b = row >> 9;
    const float* erow = emb + (size_t)row * 500;
    const float* hrow = hidden + (size_t)row * 800;
    f16* horow  = ho + (size_t)row * 640;
    f16* acrow  = aux_cat + (size_t)row * 640;
    f16* h16row = hid16 + (size_t)row * 800;

    if (t < 125) {                             // emb cols [0,500)
      float4 v = *(const float4*)(erow + 4 * t);
      f16x4 h = { f2h(v.x), f2h(v.y), f2h(v.z), f2h(v.w) };
      *(f16x4*)(horow + 4 * t) = h;
    } else if (t < 150) {                      // lang cols [500,600)
      int j = (t - 125) * 4;
      const float* lrow = lang_table + lang_ids[b] * 100;
      float4 v = *(const float4*)(lrow + j);
      f16x4 h = { f2h(v.x), f2h(v.y), f2h(v.z), f2h(v.w) };
      *(f16x4*)(horow + 500 + j) = h;
      *(f16x4*)(acrow + 500 + j) = h;
    } else if (t < 160) {                      // pad cols [600,640)
      int j = 600 + (t - 150) * 4;
      f16x4 z = { (f16)0.f, (f16)0.f, (f16)0.f, (f16)0.f };
      *(f16x4*)(horow + j) = z;
      *(f16x4*)(acrow + j) = z;
    }
    if (t < 200) {                             // hidden cols [0,800)
      float4 v = *(const float4*)(hrow + 4 * t);
      f16x4 h = { f2h(v.x), f2h(v.y), f2h(v.z), f2h(v.w) };
      *(f16x4*)(h16row + 4 * t) = h;
    }
    return;
  }

  const int wq = blk - 16384;
  if (wq < 1280) {                             // ---- weight quads ----
    int q = wq * 256 + t;                      // [0, 327680)
    const float* src = nullptr;
    f16* dst;
    if (q < 81920) {                           // W_proj [512,640] : 160 quads/row
      int n = q / 160, s = q - n * 160;
      dst = W_proj + (size_t)q * 4;
      if (s < 150 && n < 500)
        src = (n < 100 ? W_arc + (size_t)n * 600
                       : W_lab + (size_t)(n - 100) * 600) + s * 4;
    } else if (q < 184320) {                   // W_auxp [512,800] : 200 quads/row
      int q2 = q - 81920;
      int n = q2 / 200;
      dst = W_auxp + (size_t)q2 * 4;
      if (n < 500) src = W_aux + (size_t)q2 * 4;
    } else {                                   // W_heads [896,640] : 160 quads/row
      int q3 = q - 184320;
      int n = q3 / 160, s = q3 - n * 160;
      dst = W_heads + (size_t)q3 * 4;
      if (s < 150 && n < 820)
        src = (n < 20 ? W_upos + (size_t)n * 600
              : n < 320 ? W_xpos + (size_t)(n - 20) * 600
                        : W_attrs + (size_t)(n - 320) * 600) + s * 4;
    }
    f16x4 h = { (f16)0.f, (f16)0.f, (f16)0.f, (f16)0.f };
    if (src) { float4 v = *(const float4*)src; h = f16x4{ f2h(v.x), f2h(v.y), f2h(v.z), f2h(v.w) }; }
    *(f16x4*)dst = h;
    return;
  }

  // ---- biases (one block, 1920 values) ----
  for (int idx = t; idx < 1920; idx += 256) {
    if (idx < 512) {
      float v = 0.f;
      if (idx < 100)      v = b_arc[idx];
      else if (idx < 500) v = b_lab[idx - 100];
      bias_proj[idx] = v;
    } else if (idx < 1024) {
      int i = idx - 512;
      bias_aux[i] = (i < 500) ? b_aux[i] : 0.f;
    } else {
      int i = idx - 1024; float v = 0.f;
      if (i < 20)       v = b_upos[i];
      else if (i < 320) v = b_xpos[i - 20];
      else if (i < 820) v = b_attrs[i - 320];
      bias_heads[i] = v;
    }
  }
}

// ---------------------------------------------------------------------------
// MFMA GEMM: C[M,Npad] = A[M,K] * B[Npad,K]^T, 128x128 tile, 4 waves 64x64,
// BK=32, double-buffered async staging (global_load_lds w=16).
// MODE 0: tanh; cols[100,500)->out_label; cols[0,100)->fused s1/s2 dots
// MODE 1: tanh; cols[0,500)->aux_cat (f16, ldc 640)
// MODE 2: cols<20 upos | <320 xpos | <820 attrs (fp32)
// ---------------------------------------------------------------------------
template <int MODE>
__global__ __launch_bounds__(256) void gemm_mfma(
    const f16* __restrict__ A, const f16* __restrict__ B,
    const float* __restrict__ bias, const int K,
    float* __restrict__ out_label, const float* __restrict__ w_head,
    float* __restrict__ s1, float* __restrict__ s2,
    f16* __restrict__ aux_cat,
    float* __restrict__ out_upos, float* __restrict__ out_xpos,
    float* __restrict__ out_attrs)
{
  __shared__ __align__(16) f16 ldsA[2][128 * 32];
  __shared__ __align__(16) f16 ldsB[2][128 * 32];
  __shared__ float s1red[2][128], s2red[2][128];

  const int tid  = threadIdx.x;
  const int lane = tid & 63;
  const int wave = tid >> 6;          // 0..3
  const int wm = wave >> 1, wn = wave & 1;
  const int m16 = lane & 15, quad = lane >> 4;
  const int bm = blockIdx.x, bn = blockIdx.y;

  f32x4 acc[4][4] = {};

  // staging: chunk q in [0,512): row=q>>2, 8-elem group q&3; this thread's
  // lanes supply chunks q0=tid (wave-uniform LDS base wave*1024B) and q1=tid+256.
  const int q0 = tid, q1 = tid + 256;
  const f16* gA0 = A + (size_t)(bm * 128 + (q0 >> 2)) * K + (q0 & 3) * 8;
  const f16* gA1 = A + (size_t)(bm * 128 + (q1 >> 2)) * K + (q1 & 3) * 8;
  const f16* gB0 = B + (size_t)(bn * 128 + (q0 >> 2)) * K + (q0 & 3) * 8;
  const f16* gB1 = B + (size_t)(bn * 128 + (q1 >> 2)) * K + (q1 & 3) * 8;

#define STAGE(buf, k0) do {                                        \
    async16(&((uint4*)ldsA[buf])[wave * 64],       gA0 + (k0));    \
    async16(&((uint4*)ldsA[buf])[wave * 64 + 256], gA1 + (k0));    \
    async16(&((uint4*)ldsB[buf])[wave * 64],       gB0 + (k0));    \
    async16(&((uint4*)ldsB[buf])[wave * 64 + 256], gB1 + (k0));    \
  } while (0)

#define COMPUTE(buf) do {                                                        \
    f16x8 af[4], bfr[4];                                                         \
    _Pragma("unroll")                                                            \
    for (int i = 0; i < 4; ++i)                                                  \
      af[i] = *(const f16x8*)&ldsA[buf][(wm * 64 + i * 16 + m16) * 32 + quad * 8]; \
    _Pragma("unroll")                                                            \
    for (int j = 0; j < 4; ++j)                                                  \
      bfr[j] = *(const f16x8*)&ldsB[buf][(wn * 64 + j * 16 + m16) * 32 + quad * 8]; \
    _Pragma("unroll")                                                            \
    for (int i = 0; i < 4; ++i)                                                  \
      _Pragma("unroll")                                                          \
      for (int j = 0; j < 4; ++j)                                                \
        acc[i][j] = __builtin_amdgcn_mfma_f32_16x16x32_f16(af[i], bfr[j], acc[i][j], 0, 0, 0); \
  } while (0)

  STAGE(0, 0);
  __syncthreads();                    // vmcnt(0) drained -> tile 0 in LDS
  int cur = 0;
  for (int k0 = 32; k0 < K; k0 += 32) {
    STAGE(cur ^ 1, k0);               // next tile flies during compute
    COMPUTE(cur);
    __syncthreads();                  // drains lgkm (ds_reads) + vm (next tile)
    cur ^= 1;
  }
  COMPUTE(cur);                       // last tile, no trailing barrier

  // epilogue: row = bm*128 + wm*64 + i*16 + quad*4 + r ; col = bn*128 + wn*64 + j*16 + m16
  const int row0 = bm * 128 + wm * 64 + quad * 4;
  const int col0 = bn * 128 + wn * 64 + m16;

  if (MODE == 0) {
    float p1[4][4] = {}, p2[4][4] = {};
    const bool isbn0 = (bn == 0);
#pragma unroll
    for (int i = 0; i < 4; ++i) {
#pragma unroll
      for (int j = 0; j < 4; ++j) {
        const int col = col0 + j * 16;
        const float bcol = bias[col];
        float w1c = 0.f, w2c = 0.f;
        if (isbn0 && col < 100) { w1c = w_head[col]; w2c = w_head[100 + col]; }
#pragma unroll
        for (int r = 0; r < 4; ++r) {
          const int row = row0 + i * 16 + r;
          float v = tanhf(acc[i][j][r] + bcol);
          if (col >= 100 && col < 500) out_label[(size_t)row * 400 + col - 100] = v;
          p1[i][r] += v * w1c;
          p2[i][r] += v * w2c;
        }
      }
    }
    if (isbn0) {                       // block-uniform branch
#pragma unroll
      for (int d = 1; d < 16; d <<= 1) {
#pragma unroll
        for (int i = 0; i < 4; ++i)
#pragma unroll
          for (int r = 0; r < 4; ++r) {
            p1[i][r] += __shfl_xor(p1[i][r], d);
            p2[i][r] += __shfl_xor(p2[i][r], d);
          }
      }
      if (m16 == 0) {
#pragma unroll
        for (int i = 0; i < 4; ++i)
#pragma unroll
          for (int r = 0; r < 4; ++r) {
            int rl = wm * 64 + i * 16 + quad * 4 + r;
            s1red[wn][rl] = p1[i][r];
            s2red[wn][rl] = p2[i][r];
          }
      }
      __syncthreads();
      if (tid < 128)       s1[bm * 128 + tid] = s1red[0][tid] + s1red[1][tid];
      else                 s2[bm * 128 + tid - 128] = s2red[0][tid - 128] + s2red[1][tid - 128];
    }
  } else if (MODE == 1) {
#pragma unroll
    for (int i = 0; i < 4; ++i)
#pragma unroll
      for (int j = 0; j < 4; ++j) {
        const int col = col0 + j * 16;
        const float bcol = bias[col];
#pragma unroll
        for (int r = 0; r < 4; ++r) {
          const int row = row0 + i * 16 + r;
          if (col < 500) aux_cat[(size_t)row * 640 + col] = f2h(tanhf(acc[i][j][r] + bcol));
        }
      }
  } else {
#pragma unroll
    for (int i = 0; i < 4; ++i)
#pragma unroll
      for (int j = 0; j < 4; ++j) {
        const int col = col0 + j * 16;
        const float bcol = bias[col];
#pragma unroll
        for (int r = 0; r < 4; ++r) {
          const int row = row0 + i * 16 + r;
          float v = acc[i][j][r] + bcol;
          if (col < 20)        out_upos[(size_t)row * 20 + col] = v;
          else if (col < 320)  out_xpos[(size_t)row * 300 + col - 20] = v;
          else if (col < 820)  out_attrs[(size_t)row * 500 + col - 320] = v;
        }
      }
  }
#undef STAGE
#undef COMPUTE
}

// ---------------------------------------------------------------------------
// arcs[b,i,0]=0 ; arcs[b,i,1+j] = s1[b,i] + s2[b,j] + b_head   (one block/row)
// ---------------------------------------------------------------------------
__global__ __launch_bounds__(256) void arcs_kernel(
    const float* __restrict__ s1, const float* __restrict__ s2,
    const float* __restrict__ b_head, float* __restrict__ out)
{
  const int row = blockIdx.x;                 // 16384 = b*512 + i
  const int b = row >> 9;
  const float s1v = s1[row] + b_head[0];
  const float* s2b = s2 + ((size_t)b << 9);
  float* orow = out + (size_t)row * 513;
  if (threadIdx.x == 0) orow[0] = 0.f;
#pragma unroll
  for (int j = threadIdx.x; j < 512; j += 256)
    orow[1 + j] = s1v + s2b[j];
}

// ---------------------------------------------------------------------------
extern "C" void kernel_launch(void* const* d_in, const int* in_sizes, int n_in,
                              void* d_out, int out_size, void* d_ws, size_t ws_size,
                              hipStream_t stream)
{
  const float* emb      = (const float*)d_in[0];   // [32,512,500]
  const float* hidden   = (const float*)d_in[1];   // [32,512,800]
  const int*   lang_ids = (const int*)d_in[2];     // [32]
  const float* lang_tab = (const float*)d_in[3];   // [8,100]
  const float* W_arc  = (const float*)d_in[4];
  const float* b_arc  = (const float*)d_in[5];
  const float* W_lab  = (const float*)d_in[6];
  const float* b_lab  = (const float*)d_in[7];
  const float* w_head = (const float*)d_in[8];
  const float* b_head = (const float*)d_in[9];
  const float* W_aux  = (const float*)d_in[10];
  const float* b_aux  = (const float*)d_in[11];
  const float* W_upos = (const float*)d_in[12];
  const float* b_upos = (const float*)d_in[13];
  const float* W_xpos = (const float*)d_in[14];
  const float* b_xpos = (const float*)d_in[15];
  const float* W_attrs = (const float*)d_in[16];
  const float* b_attrs = (const float*)d_in[17];

  char* ws = (char*)d_ws;
  f16* ho      = (f16*)(ws + 0);                  // 16384*640*2 = 20,971,520
  f16* aux_cat = (f16*)(ws + 20971520);           // 16384*640*2
  f16* hid16   = (f16*)(ws + 41943040);           // 16384*800*2 = 26,214,400
  f16* W_proj  = (f16*)(ws + 68157440);           // 512*640*2
  f16* W_auxp  = (f16*)(ws + 68812800);           // 512*800*2
  f16* W_heads = (f16*)(ws + 69632000);           // 896*640*2
  float* bias_proj  = (float*)(ws + 70778880);    // 512*4
  float* bias_aux   = (float*)(ws + 70780928);    // 512*4
  float* bias_heads = (float*)(ws + 70782976);    // 896*4
  float* s1         = (float*)(ws + 70786560);    // 16384*4
  float* s2         = (float*)(ws + 70852096);    // 16384*4
  // total ws use: 70,917,632 bytes (ws_size ~454 MB)

  float* out       = (float*)d_out;
  float* out_arcs  = out;                 // 8,404,992
  float* out_label = out + 8404992;       // 6,553,600
  float* out_upos  = out + 14958592;      //   327,680
  float* out_xpos  = out + 15286272;      // 4,915,200
  float* out_attrs = out + 20201472;      // 8,192,000

  setup_kernel<<<17665, 256, 0, stream>>>(
      emb, hidden, lang_tab, lang_ids,
      W_arc, b_arc, W_lab, b_lab, W_aux, b_aux,
      W_upos, b_upos, W_xpos, b_xpos, W_attrs, b_attrs,
      ho, aux_cat, hid16, W_proj, W_auxp, W_heads,
      bias_proj, bias_aux, bias_heads);

  gemm_mfma<0><<<dim3(128, 4), 256, 0, stream>>>(
      ho, W_proj, bias_proj, 640,
      out_label, w_head, s1, s2, nullptr, nullptr, nullptr, nullptr);

  arcs_kernel<<<16384, 256, 0, stream>>>(s1, s2, b_head, out_arcs);

  gemm_mfma<1><<<dim3(128, 4), 256, 0, stream>>>(
      hid16, W_auxp, bias_aux, 800,
      nullptr, nullptr, nullptr, nullptr, aux_cat, nullptr, nullptr, nullptr);

  gemm_mfma<2><<<dim3(128, 7), 256, 0, stream>>>(
      aux_cat, W_heads, bias_heads, 640,
      nullptr, nullptr, nullptr, nullptr, nullptr, out_upos, out_xpos, out_attrs);
}